// Round 1
// baseline (567.276 us; speedup 1.0000x reference)
//
#include <hip/hip_runtime.h>

#define TAGS 64
#define SOS_IDX 1
#define EOS_IDX 2

typedef __attribute__((ext_vector_type(2))) float f2;

// quad_perm DPP: x1 = swap bit0 [1,0,3,2]; x2 = swap bit1 [2,3,0,1]
#define DPP_X1 0xB1
#define DPP_X2 0x4E
#define DPPF(v, ctrl) \
    __int_as_float(__builtin_amdgcn_mov_dpp(__float_as_int(v), (ctrl), 0xF, 0xF, true))

__device__ __forceinline__ float rl(float v, int l) {
    return __int_as_float(__builtin_amdgcn_readlane(__float_as_int(v), l));
}

// TWO batches per wave, software-staggered by half a step:
//   [S1: A publish+read] [S2: B tree] [S3: B publish+read] [S4: A tree]
// Each batch's LDS round trip (~130-150 cy) is hidden under the OTHER
// batch's fma tree (~130 cy of issue). DS ops complete in order, so the
// compiler's counted lgkmcnt lets S2 proceed while A's reads are in
// flight. Per-batch arithmetic is bit-identical to the single-batch
// kernel (absmax must stay 0.0).
__global__ __launch_bounds__(64, 1) void crf_fwd_kernel(
    const float* __restrict__ h,
    const float* __restrict__ mask,
    const float* __restrict__ trans,
    float* __restrict__ out,
    int S)
{
    const int lane = threadIdx.x;
    const int g = lane >> 2;
    const int c = lane & 3;
    const int b0 = blockIdx.x * 2;      // B is even (512)
    const int b1 = b0 + 1;

    __shared__ __align__(16) float uA_sh[TAGS];
    __shared__ __align__(16) float uB_sh[TAGS];

    // E fragment: slot k holds exp(trans[4g + (c^k)][16c .. 16c+16)) as 8 f2.
    // Shared by both batches (same trans).
    f2 ew2[4][8];
    #pragma unroll
    for (int k = 0; k < 4; ++k) {
        const int row = 4 * g + (c ^ k);
        const float4* tr = reinterpret_cast<const float4*>(trans + row * TAGS + 16 * c);
        #pragma unroll
        for (int q = 0; q < 4; ++q) {
            float4 v = tr[q];
            f2 lo, hi;
            lo.x = __expf(v.x); lo.y = __expf(v.y);   // exp(-10000) -> 0 exact
            hi.x = __expf(v.z); hi.y = __expf(v.w);
            ew2[k][2*q]   = lo;
            ew2[k][2*q+1] = hi;
        }
    }

    const float* hA = h + (size_t)b0 * (size_t)S * TAGS + lane;
    const float* hB = h + (size_t)b1 * (size_t)S * TAGS + lane;
    const float* mA = mask + (size_t)b0 * (size_t)S;
    const float* mB = mask + (size_t)b1 * (size_t)S;

    float xA = (lane == SOS_IDX) ? 1.0f : 0.0f;  // exp(score0)
    float xB = xA;
    float LsA = 0.0f, LsB = 0.0f;                // sum of log2(z), per batch

    // h prefetch, depth 8 per batch (coalesced 256B/wave/step/batch)
    float hbufA[8], hbufB[8];
    #pragma unroll
    for (int q = 0; q < 8; ++q) {
        int t = (q < S) ? q : (S - 1);
        hbufA[q] = hA[(size_t)t * TAGS];
        hbufB[q] = hB[(size_t)t * TAGS];
    }

    const int NC = S >> 6;                       // S % 64 == 0 (S = 1024)
    float mregA = mA[lane];
    float mregB = mB[lane];

    const float4* u4A = reinterpret_cast<const float4*>(uA_sh);
    const float4* u4B = reinterpret_cast<const float4*>(uB_sh);

    // ---- prime batch B's LDS pipeline (publish x_0, read) ----
    uB_sh[lane] = xB;
    float zrB = uB_sh[3];
    float4 cb0 = u4B[(c << 2) + 0];
    float4 cb1 = u4B[(c << 2) + 1];
    float4 cb2 = u4B[(c << 2) + 2];
    float4 cb3 = u4B[(c << 2) + 3];
    __builtin_amdgcn_wave_barrier();

    for (int ch = 0; ch < NC; ++ch) {
        const int cn = (ch + 1 < NC) ? (ch + 1) : ch;
        float mnA = mA[(size_t)cn * 64 + lane];   // used 64 steps from now
        float mnB = mB[(size_t)cn * 64 + lane];

        for (int t0 = 0; t0 < 64; t0 += 8) {
            float ehqA[8], ehqB[8];
            #pragma unroll
            for (int q = 0; q < 8; ++q) {
                ehqA[q] = __expf(hbufA[q]);
                ehqB[q] = __expf(hbufB[q]);
            }
            const int base = ch * 64 + t0 + 8;
            #pragma unroll
            for (int q = 0; q < 8; ++q) {
                int tn = base + q;
                if (tn > S - 1) tn = S - 1;
                hbufA[q] = hA[(size_t)tn * TAGS];
                hbufB[q] = hB[(size_t)tn * TAGS];
            }

            #pragma unroll
            for (int q = 0; q < 8; ++q) {
                // ---- S1: A publish + read (RT hidden under S2+S3) ----
                uA_sh[lane] = xA;
                const float zrA = uA_sh[3];        // ds_read_b32, broadcast
                float4 ca0 = u4A[(c << 2) + 0];
                float4 ca1 = u4A[(c << 2) + 1];
                float4 ca2 = u4A[(c << 2) + 2];
                float4 ca3 = u4A[(c << 2) + 3];
                __builtin_amdgcn_wave_barrier();

                // ---- S2: B tree (cb*/zrB issued in previous S3) ----
                {
                    const float m = rl(mregB, t0 + q);          // cold reg
                    const float z = (zrB > 0.0f) ? zrB : 1.0f;  // t=0: x[3]==0
                    const float s  = ehqB[q] * __builtin_amdgcn_rcpf(z);
                    const float lg = __log2f(z);

                    f2 uu[8];
                    uu[0].x = cb0.x; uu[0].y = cb0.y;  uu[1].x = cb0.z; uu[1].y = cb0.w;
                    uu[2].x = cb1.x; uu[2].y = cb1.y;  uu[3].x = cb1.z; uu[3].y = cb1.w;
                    uu[4].x = cb2.x; uu[4].y = cb2.y;  uu[5].x = cb2.z; uu[5].y = cb2.w;
                    uu[6].x = cb3.x; uu[6].y = cb3.y;  uu[7].x = cb3.z; uu[7].y = cb3.w;

                    float pp[4];
                    #pragma unroll
                    for (int k = 0; k < 4; ++k) {
                        f2 a    = ew2[k][0] * uu[0];
                        f2 bacc = ew2[k][1] * uu[1];
                        a    = __builtin_elementwise_fma(ew2[k][2], uu[2], a);
                        bacc = __builtin_elementwise_fma(ew2[k][3], uu[3], bacc);
                        a    = __builtin_elementwise_fma(ew2[k][4], uu[4], a);
                        bacc = __builtin_elementwise_fma(ew2[k][5], uu[5], bacc);
                        a    = __builtin_elementwise_fma(ew2[k][6], uu[6], a);
                        bacc = __builtin_elementwise_fma(ew2[k][7], uu[7], bacc);
                        a = a + bacc;
                        pp[k] = a.x + a.y;
                    }
                    pp[0] += DPPF(pp[1], DPP_X1);
                    pp[2] += DPPF(pp[3], DPP_X1);
                    pp[0] += DPPF(pp[2], DPP_X2);

                    const float xnew = pp[0] * s;
                    const bool mm = (m != 0.0f);                // uniform
                    xB  = mm ? xnew : xB;
                    LsB = mm ? (LsB + lg) : LsB;
                }
                __builtin_amdgcn_wave_barrier();

                // ---- S3: B publish + read (RT hidden under S4 + next S1) ----
                uB_sh[lane] = xB;
                zrB = uB_sh[3];
                cb0 = u4B[(c << 2) + 0];
                cb1 = u4B[(c << 2) + 1];
                cb2 = u4B[(c << 2) + 2];
                cb3 = u4B[(c << 2) + 3];
                __builtin_amdgcn_wave_barrier();

                // ---- S4: A tree (ca*/zrA issued in S1) ----
                {
                    const float m = rl(mregA, t0 + q);
                    const float z = (zrA > 0.0f) ? zrA : 1.0f;
                    const float s  = ehqA[q] * __builtin_amdgcn_rcpf(z);
                    const float lg = __log2f(z);

                    f2 uu[8];
                    uu[0].x = ca0.x; uu[0].y = ca0.y;  uu[1].x = ca0.z; uu[1].y = ca0.w;
                    uu[2].x = ca1.x; uu[2].y = ca1.y;  uu[3].x = ca1.z; uu[3].y = ca1.w;
                    uu[4].x = ca2.x; uu[4].y = ca2.y;  uu[5].x = ca2.z; uu[5].y = ca2.w;
                    uu[6].x = ca3.x; uu[6].y = ca3.y;  uu[7].x = ca3.z; uu[7].y = ca3.w;

                    float pp[4];
                    #pragma unroll
                    for (int k = 0; k < 4; ++k) {
                        f2 a    = ew2[k][0] * uu[0];
                        f2 bacc = ew2[k][1] * uu[1];
                        a    = __builtin_elementwise_fma(ew2[k][2], uu[2], a);
                        bacc = __builtin_elementwise_fma(ew2[k][3], uu[3], bacc);
                        a    = __builtin_elementwise_fma(ew2[k][4], uu[4], a);
                        bacc = __builtin_elementwise_fma(ew2[k][5], uu[5], bacc);
                        a    = __builtin_elementwise_fma(ew2[k][6], uu[6], a);
                        bacc = __builtin_elementwise_fma(ew2[k][7], uu[7], bacc);
                        a = a + bacc;
                        pp[k] = a.x + a.y;
                    }
                    pp[0] += DPPF(pp[1], DPP_X1);
                    pp[2] += DPPF(pp[3], DPP_X1);
                    pp[0] += DPPF(pp[2], DPP_X2);

                    const float xnew = pp[0] * s;
                    const bool mm = (m != 0.0f);
                    xA  = mm ? xnew : xA;
                    LsA = mm ? (LsA + lg) : LsA;
                }
                __builtin_amdgcn_wave_barrier();
            }
        }
        mregA = mnA;
        mregB = mnB;
    }

    // out[b] = ln2*Ls + log(sum_i x[i] * exp(trans[EOS, i]))
    const float et = __expf(trans[EOS_IDX * TAGS + lane]);
    float vA = xA * et;
    float vB = xB * et;
    #pragma unroll
    for (int off = 32; off > 0; off >>= 1) {
        vA += __shfl_xor(vA, off, 64);
        vB += __shfl_xor(vB, off, 64);
    }
    if (lane == 0) {
        out[b0] = 0.69314718055994531f * LsA + __logf(vA);
        out[b1] = 0.69314718055994531f * LsB + __logf(vB);
    }
}

extern "C" void kernel_launch(void* const* d_in, const int* in_sizes, int n_in,
                              void* d_out, int out_size, void* d_ws, size_t ws_size,
                              hipStream_t stream) {
    const float* h     = (const float*)d_in[0];
    const float* mask  = (const float*)d_in[1];
    const float* trans = (const float*)d_in[2];
    float* out = (float*)d_out;

    const int B = out_size;                 // 512 (even)
    const int S = in_sizes[1] / B;          // 1024  (mask is B*S)

    crf_fwd_kernel<<<B / 2, 64, 0, stream>>>(h, mask, trans, out, S);
}

// Round 2
// 435.931 us; speedup vs baseline: 1.3013x; 1.3013x over previous
//
#include <hip/hip_runtime.h>
#include <stdint.h>

#define TAGS 64
#define SOS_IDX 1
#define EOS_IDX 2

typedef __attribute__((ext_vector_type(2))) float f2;
typedef __attribute__((ext_vector_type(4))) float f4;

// quad_perm DPP: x1 = swap bit0 [1,0,3,2]; x2 = swap bit1 [2,3,0,1]
#define DPP_X1 0xB1
#define DPP_X2 0x4E
#define DPPF(v, ctrl) \
    __int_as_float(__builtin_amdgcn_mov_dpp(__float_as_int(v), (ctrl), 0xF, 0xF, true))

__device__ __forceinline__ float rl(float v, int l) {
    return __int_as_float(__builtin_amdgcn_readlane(__float_as_int(v), l));
}

// Publish x to LDS and issue the 6 in-order DS ops (1 write, 1 b32 z-broadcast,
// 4 b128). All volatile asm: program order is pinned, reads cannot be sunk to
// their uses by the scheduler (R1's failure mode), and the results MUST be
// allocated live across the opposite stream's tree.
#define PUBLISH_READ(WR, ZA, RD, X, ZR, C0, C1, C2, C3) do {                   \
    asm volatile("ds_write_b32 %0, %1" :: "v"(WR), "v"(X));                    \
    asm volatile("ds_read_b32 %0, %1"            : "=v"(ZR) : "v"(ZA));        \
    asm volatile("ds_read_b128 %0, %1"           : "=v"(C0) : "v"(RD));        \
    asm volatile("ds_read_b128 %0, %1 offset:16" : "=v"(C1) : "v"(RD));        \
    asm volatile("ds_read_b128 %0, %1 offset:32" : "=v"(C2) : "v"(RD));        \
    asm volatile("ds_read_b128 %0, %1 offset:48" : "=v"(C3) : "v"(RD));        \
} while (0)

// DS completes in-order within a wave: with 6 ops just issued by the CURRENT
// stream, waiting lgkmcnt<=6 drains exactly the 6 OLDER ops of the OTHER
// stream. sched_barrier(0) keeps the (register-only) tree from hoisting above
// the wait (guide rule #18).
#define WAIT_OTHER() do {                                                      \
    asm volatile("s_waitcnt lgkmcnt(6)");                                      \
    __builtin_amdgcn_sched_barrier(0);                                         \
} while (0)

// One CRF step in the exp domain (bit-identical to the single-batch kernel):
// z = x_prev[3]; s = exp(h_t)*rcp(z); x' = (E x)*s; Ls += log2(z), gated by m.
#define TREE(ZR, EH, MV, C0, C1, C2, C3, X, LS) do {                           \
    const float m_ = (MV);                                                     \
    const float z_ = ((ZR) > 0.0f) ? (ZR) : 1.0f;                              \
    const float s_ = (EH) * __builtin_amdgcn_rcpf(z_);                         \
    const float lg_ = __log2f(z_);                                             \
    f2 uu[8];                                                                  \
    uu[0].x = (C0).x; uu[0].y = (C0).y;  uu[1].x = (C0).z; uu[1].y = (C0).w;   \
    uu[2].x = (C1).x; uu[2].y = (C1).y;  uu[3].x = (C1).z; uu[3].y = (C1).w;   \
    uu[4].x = (C2).x; uu[4].y = (C2).y;  uu[5].x = (C2).z; uu[5].y = (C2).w;   \
    uu[6].x = (C3).x; uu[6].y = (C3).y;  uu[7].x = (C3).z; uu[7].y = (C3).w;   \
    float pp[4];                                                               \
    _Pragma("unroll")                                                          \
    for (int k = 0; k < 4; ++k) {                                              \
        f2 a    = ew2[k][0] * uu[0];                                           \
        f2 bacc = ew2[k][1] * uu[1];                                           \
        a    = __builtin_elementwise_fma(ew2[k][2], uu[2], a);                 \
        bacc = __builtin_elementwise_fma(ew2[k][3], uu[3], bacc);              \
        a    = __builtin_elementwise_fma(ew2[k][4], uu[4], a);                 \
        bacc = __builtin_elementwise_fma(ew2[k][5], uu[5], bacc);              \
        a    = __builtin_elementwise_fma(ew2[k][6], uu[6], a);                 \
        bacc = __builtin_elementwise_fma(ew2[k][7], uu[7], bacc);              \
        a = a + bacc;                                                          \
        pp[k] = a.x + a.y;                                                     \
    }                                                                          \
    pp[0] += DPPF(pp[1], DPP_X1);                                              \
    pp[2] += DPPF(pp[3], DPP_X1);                                              \
    pp[0] += DPPF(pp[2], DPP_X2);                                              \
    const float xn_ = pp[0] * s_;                                              \
    const bool mm_ = (m_ != 0.0f);                                             \
    (X)  = mm_ ? xn_ : (X);                                                    \
    (LS) = mm_ ? ((LS) + lg_) : (LS);                                          \
} while (0)

// TWO batches per wave, software-staggered by half a step; the LDS ops and
// counted waits are inline asm so the compiler can neither sink the reads
// (R1 failure: VGPR=80 proved it scheduled reads next to uses) nor emit
// conservative lgkmcnt(0).
__global__ __launch_bounds__(64, 1) void crf_fwd_kernel(
    const float* __restrict__ h,
    const float* __restrict__ mask,
    const float* __restrict__ trans,
    float* __restrict__ out,
    int S)
{
    const int lane = threadIdx.x;
    const int g = lane >> 2;
    const int c = lane & 3;
    const int b0 = blockIdx.x * 2;      // B is even (512)
    const int b1 = b0 + 1;

    __shared__ __align__(16) float uA_sh[TAGS];
    __shared__ __align__(16) float uB_sh[TAGS];

    // LDS byte offsets (generic shared addr = aperture_hi32 | offset_lo32).
    const uint32_t baseA = (uint32_t)(uintptr_t)(&uA_sh[0]);
    const uint32_t baseB = (uint32_t)(uintptr_t)(&uB_sh[0]);
    const uint32_t wrA = baseA + ((uint32_t)lane << 2);
    const uint32_t wrB = baseB + ((uint32_t)lane << 2);
    const uint32_t rdA = baseA + ((uint32_t)c << 6);   // this lane's 16 u's
    const uint32_t rdB = baseB + ((uint32_t)c << 6);
    const uint32_t zaA = baseA + 12;                   // u[3] broadcast
    const uint32_t zaB = baseB + 12;

    // E fragment: slot k holds exp(trans[4g + (c^k)][16c .. 16c+16)) as 8 f2.
    f2 ew2[4][8];
    #pragma unroll
    for (int k = 0; k < 4; ++k) {
        const int row = 4 * g + (c ^ k);
        const f4* tr = reinterpret_cast<const f4*>(trans + row * TAGS + 16 * c);
        #pragma unroll
        for (int q = 0; q < 4; ++q) {
            f4 v = tr[q];
            f2 lo, hi;
            lo.x = __expf(v.x); lo.y = __expf(v.y);   // exp(-10000) -> 0 exact
            hi.x = __expf(v.z); hi.y = __expf(v.w);
            ew2[k][2*q]   = lo;
            ew2[k][2*q+1] = hi;
        }
    }

    const float* hA = h + (size_t)b0 * (size_t)S * TAGS + lane;
    const float* hB = h + (size_t)b1 * (size_t)S * TAGS + lane;
    const float* mA = mask + (size_t)b0 * (size_t)S;
    const float* mB = mask + (size_t)b1 * (size_t)S;

    float xA = (lane == SOS_IDX) ? 1.0f : 0.0f;  // exp(score0)
    float xB = xA;
    float LsA = 0.0f, LsB = 0.0f;                // sum of log2(z), per batch

    // h prefetch, depth 8 per batch (coalesced 256B/wave/step/batch)
    float hbufA[8], hbufB[8];
    #pragma unroll
    for (int q = 0; q < 8; ++q) {
        int t = (q < S) ? q : (S - 1);
        hbufA[q] = hA[(size_t)t * TAGS];
        hbufB[q] = hB[(size_t)t * TAGS];
    }

    const int NC = S >> 6;                       // S % 64 == 0 (S = 1024)
    float mregA = mA[lane];
    float mregB = mB[lane];

    // ---- prime stream B: publish x_0, issue its 6 DS ops ----
    float zrB; f4 cb0, cb1, cb2, cb3;
    PUBLISH_READ(wrB, zaB, rdB, xB, zrB, cb0, cb1, cb2, cb3);

    for (int ch = 0; ch < NC; ++ch) {
        const int cn = (ch + 1 < NC) ? (ch + 1) : ch;
        float mnA = mA[(size_t)cn * 64 + lane];   // used 64 steps from now
        float mnB = mB[(size_t)cn * 64 + lane];

        for (int t0 = 0; t0 < 64; t0 += 8) {
            float ehqA[8], ehqB[8];
            #pragma unroll
            for (int q = 0; q < 8; ++q) {
                ehqA[q] = __expf(hbufA[q]);
                ehqB[q] = __expf(hbufB[q]);
            }
            const int base = ch * 64 + t0 + 8;
            #pragma unroll
            for (int q = 0; q < 8; ++q) {
                int tn = base + q;
                if (tn > S - 1) tn = S - 1;
                hbufA[q] = hA[(size_t)tn * TAGS];
                hbufB[q] = hB[(size_t)tn * TAGS];
            }

            #pragma unroll
            for (int q = 0; q < 8; ++q) {
                // S1: A publish + issue reads (RT flies under tree B)
                float zrA; f4 ca0, ca1, ca2, ca3;
                PUBLISH_READ(wrA, zaA, rdA, xA, zrA, ca0, ca1, ca2, ca3);
                WAIT_OTHER();   // drains B's 6 older ops only
                // S2: tree B
                TREE(zrB, ehqB[q], rl(mregB, t0 + q), cb0, cb1, cb2, cb3, xB, LsB);
                // S3: B publish + issue reads (RT flies under tree A)
                PUBLISH_READ(wrB, zaB, rdB, xB, zrB, cb0, cb1, cb2, cb3);
                WAIT_OTHER();   // drains A's 6 older ops only
                // S4: tree A
                TREE(zrA, ehqA[q], rl(mregA, t0 + q), ca0, ca1, ca2, ca3, xA, LsA);
            }
        }
        mregA = mnA;
        mregB = mnB;
    }

    // drain the dangling B reads before compiler-generated cross-lane ops
    asm volatile("s_waitcnt lgkmcnt(0)");

    // out[b] = ln2*Ls + log(sum_i x[i] * exp(trans[EOS, i]))
    const float et = __expf(trans[EOS_IDX * TAGS + lane]);
    float vA = xA * et;
    float vB = xB * et;
    #pragma unroll
    for (int off = 32; off > 0; off >>= 1) {
        vA += __shfl_xor(vA, off, 64);
        vB += __shfl_xor(vB, off, 64);
    }
    if (lane == 0) {
        out[b0] = 0.69314718055994531f * LsA + __logf(vA);
        out[b1] = 0.69314718055994531f * LsB + __logf(vB);
    }
}

extern "C" void kernel_launch(void* const* d_in, const int* in_sizes, int n_in,
                              void* d_out, int out_size, void* d_ws, size_t ws_size,
                              hipStream_t stream) {
    const float* h     = (const float*)d_in[0];
    const float* mask  = (const float*)d_in[1];
    const float* trans = (const float*)d_in[2];
    float* out = (float*)d_out;

    const int B = out_size;                 // 512 (even)
    const int S = in_sizes[1] / B;          // 1024  (mask is B*S)

    crf_fwd_kernel<<<B / 2, 64, 0, stream>>>(h, mask, trans, out, S);
}

// Round 3
// 410.290 us; speedup vs baseline: 1.3826x; 1.0625x over previous
//
#include <hip/hip_runtime.h>
#include <stdint.h>

#define TAGS 64
#define SOS_IDX 1
#define EOS_IDX 2

typedef __attribute__((ext_vector_type(2))) float f2;

// quad_perm DPP: x1 = swap bit0 [1,0,3,2]; x2 = swap bit1 [2,3,0,1]
#define DPP_X1 0xB1
#define DPP_X2 0x4E
#define DPPF(v, ctrl) \
    __int_as_float(__builtin_amdgcn_mov_dpp(__float_as_int(v), (ctrl), 0xF, 0xF, true))

__device__ __forceinline__ float rl(float v, int l) {
    return __int_as_float(__builtin_amdgcn_readlane(__float_as_int(v), l));
}

// ONE sequence per block, TWO waves per block. Wave w owns output rows
// [32w, 32w+32): each lane computes 2 rows x 16 cols (half of R0's tree).
// State x (64 floats, exp-domain) lives in DOUBLE-BUFFERED LDS: step t reads
// xb[t&1], writes xb[(t+1)&1], one __syncthreads per step (visibility only;
// double-buffering removes the read-overwrite race, and each wave's own
// lgkmcnt(0)-before-barrier drains its reads before anyone can overwrite).
// 512 blocks x 2 waves = 1024 waves = one wave on every SIMD of the chip.
// All per-value arithmetic is bit-identical to the verified R0 kernel
// (same intra-lane chains; cross-lane combine differs only by commutations).
__global__ __launch_bounds__(128, 1) void crf_fwd_kernel(
    const float* __restrict__ h,
    const float* __restrict__ mask,
    const float* __restrict__ trans,
    float* __restrict__ out,
    int S)
{
    const int b    = blockIdx.x;
    const int tid  = threadIdx.x;
    const int w    = tid >> 6;          // wave 0/1
    const int lane = tid & 63;
    const int g    = lane >> 2;
    const int c    = lane & 3;
    const int half = c & 1;
    const int row  = 32 * w + 2 * g + half;   // tag owned by this lane

    __shared__ __align__(16) float xb0[TAGS];   // state t, t even
    __shared__ __align__(16) float xb1[TAGS];   // state t, t odd
    __shared__ float dump[128];                 // sink for duplicate writers

    // ew2[k]: exp(trans[32w + 2g + (half^k)][16c .. 16c+16)) as 8 f2.
    f2 ew2[2][8];
    #pragma unroll
    for (int k = 0; k < 2; ++k) {
        const int r = 32 * w + 2 * g + (half ^ k);
        const float4* tr = reinterpret_cast<const float4*>(trans + r * TAGS + 16 * c);
        #pragma unroll
        for (int q = 0; q < 4; ++q) {
            float4 v = tr[q];
            f2 lo, hi;
            lo.x = __expf(v.x); lo.y = __expf(v.y);   // exp(-10000) -> 0 exact
            hi.x = __expf(v.z); hi.y = __expf(v.w);
            ew2[k][2*q]   = lo;
            ew2[k][2*q+1] = hi;
        }
    }

    const float* hb = h + (size_t)b * (size_t)S * TAGS + row;   // this row's h
    const float* mb = mask + (size_t)b * (size_t)S;

    float x  = (row == SOS_IDX) ? 1.0f : 0.0f;   // exp-domain state for 'row'
    float Ls = 0.0f;                             // sum of log2(z), uniform

    if (tid < 64) xb0[tid] = (tid == SOS_IDX) ? 1.0f : 0.0f;   // state 0

    // h prefetch, depth 8 (one float per lane per step)
    float hbuf[8];
    #pragma unroll
    for (int q = 0; q < 8; ++q) {
        int t = (q < S) ? q : (S - 1);
        hbuf[q] = hb[(size_t)t * TAGS];
    }

    const int NC = S >> 6;                       // S % 64 == 0 (S = 1024)
    float mreg = mb[lane];

    const float4* u40 = reinterpret_cast<const float4*>(xb0);
    const float4* u41 = reinterpret_cast<const float4*>(xb1);
    // Writers: lanes c<2 publish rows 2g+{0,1}; c>=2 lanes are duplicates and
    // write to a per-lane dump slot (address select is loop-invariant).
    float* wp0 = (c < 2) ? &xb0[row] : &dump[tid];   // writes INTO buffer 0
    float* wp1 = (c < 2) ? &xb1[row] : &dump[tid];   // writes INTO buffer 1

    __syncthreads();    // state 0 visible

    for (int ch = 0; ch < NC; ++ch) {
        const int cn = (ch + 1 < NC) ? (ch + 1) : ch;
        float mreg_next = mb[(size_t)cn * 64 + lane];   // used 64 steps later

        for (int t0 = 0; t0 < 64; t0 += 8) {
            float ehq[8];
            #pragma unroll
            for (int q = 0; q < 8; ++q) ehq[q] = __expf(hbuf[q]);
            const int base = ch * 64 + t0 + 8;
            #pragma unroll
            for (int q = 0; q < 8; ++q) {
                int tn = base + q;
                if (tn > S - 1) tn = S - 1;
                hbuf[q] = hb[(size_t)tn * TAGS];
            }

            #pragma unroll
            for (int q = 0; q < 8; ++q) {
                // parity: t = ch*64+t0+q, (ch*64+t0) even -> t&1 == q&1
                const float*  zsrc = (q & 1) ? xb1 : xb0;
                const float4* u4   = (q & 1) ? u41 : u40;
                float*        wp   = (q & 1) ? wp0 : wp1;   // write buf[(t+1)&1]

                const float zr = zsrc[3];                   // b32 broadcast first
                float4 cc0 = u4[(c << 2) + 0];
                float4 cc1 = u4[(c << 2) + 1];
                float4 cc2 = u4[(c << 2) + 2];
                float4 cc3 = u4[(c << 2) + 3];

                // off-chain: executes under the b128 wait window
                const float m  = rl(mreg, t0 + q);          // cold reg, uniform
                const float z  = (zr > 0.0f) ? zr : 1.0f;   // only t=0 has x[3]==0
                const float s  = ehq[q] * __builtin_amdgcn_rcpf(z);
                const float lg = __log2f(z);

                f2 uu[8];
                uu[0].x = cc0.x; uu[0].y = cc0.y;  uu[1].x = cc0.z; uu[1].y = cc0.w;
                uu[2].x = cc1.x; uu[2].y = cc1.y;  uu[3].x = cc1.z; uu[3].y = cc1.w;
                uu[4].x = cc2.x; uu[4].y = cc2.y;  uu[5].x = cc2.z; uu[5].y = cc2.w;
                uu[6].x = cc3.x; uu[6].y = cc3.y;  uu[7].x = cc3.z; uu[7].y = cc3.w;

                float pp[2];
                #pragma unroll
                for (int k = 0; k < 2; ++k) {
                    f2 a    = ew2[k][0] * uu[0];
                    f2 bacc = ew2[k][1] * uu[1];
                    a    = __builtin_elementwise_fma(ew2[k][2], uu[2], a);
                    bacc = __builtin_elementwise_fma(ew2[k][3], uu[3], bacc);
                    a    = __builtin_elementwise_fma(ew2[k][4], uu[4], a);
                    bacc = __builtin_elementwise_fma(ew2[k][5], uu[5], bacc);
                    a    = __builtin_elementwise_fma(ew2[k][6], uu[6], a);
                    bacc = __builtin_elementwise_fma(ew2[k][7], uu[7], bacc);
                    a = a + bacc;
                    pp[k] = a.x + a.y;
                }
                // quad combine: (B_c + B_{c^1}) + (B_{c^2} + B_{c^3})
                pp[0] += DPPF(pp[1], DPP_X1);
                pp[0] += DPPF(pp[0], DPP_X2);

                const float xnew = pp[0] * s;
                const bool mm = (m != 0.0f);                // uniform
                x  = mm ? xnew : x;
                Ls = mm ? (Ls + lg) : Ls;

                *wp = x;                                    // publish state t+1
                __syncthreads();                            // visibility
            }
        }
        mreg = mreg_next;
    }

    // Final state S sits in xb[S&1]; last __syncthreads made it visible.
    const float* fin = (S & 1) ? xb1 : xb0;
    const float xf = fin[lane];
    float v = xf * __expf(trans[EOS_IDX * TAGS + lane]);
    #pragma unroll
    for (int off = 32; off > 0; off >>= 1) v += __shfl_xor(v, off, 64);
    if (tid == 0) out[b] = 0.69314718055994531f * Ls + __logf(v);
}

extern "C" void kernel_launch(void* const* d_in, const int* in_sizes, int n_in,
                              void* d_out, int out_size, void* d_ws, size_t ws_size,
                              hipStream_t stream) {
    const float* h     = (const float*)d_in[0];
    const float* mask  = (const float*)d_in[1];
    const float* trans = (const float*)d_in[2];
    float* out = (float*)d_out;

    const int B = out_size;                 // 512
    const int S = in_sizes[1] / B;          // 1024  (mask is B*S)

    crf_fwd_kernel<<<B, 128, 0, stream>>>(h, mask, trans, out, S);
}

// Round 5
// 366.215 us; speedup vs baseline: 1.5490x; 1.1204x over previous
//
#include <hip/hip_runtime.h>
#include <stdint.h>

#define TAGS 64
#define SOS_IDX 1
#define EOS_IDX 2

typedef __attribute__((ext_vector_type(2))) float f2;
typedef __attribute__((ext_vector_type(2))) unsigned int u2;

// DPP ctrl: quad_perm xor patterns + row mirrors (all involutions)
#define DPP_X1   0xB1    // quad_perm [1,0,3,2]  lane^1
#define DPP_X2   0x4E    // quad_perm [2,3,0,1]  lane^2
#define DPP_X3   0x1B    // quad_perm [3,2,1,0]  lane^3
#define DPP_MIR  0x140   // row_mirror        lane^15 (within 16)
#define DPP_HMIR 0x141   // row_half_mirror   lane^7  (within 16)
#define DPPF(v, ctrl) \
    __int_as_float(__builtin_amdgcn_mov_dpp(__float_as_int(v), (ctrl), 0xF, 0xF, true))

__device__ __forceinline__ float rl(float v, int l) {
    return __int_as_float(__builtin_amdgcn_readlane(__float_as_int(v), l));
}

// Value of v at lane^16, VALU-only. v_permlane16_swap_b32 swaps the odd
// 16-rows of op0 with the even 16-rows of op1. With both ops = v:
// res0 = rows[v0,v0,v2,v2], res1 = rows[v1,v1,v3,v3]; select by row parity.
__device__ __forceinline__ float xor16f(float v, bool odd16) {
#if __has_builtin(__builtin_amdgcn_permlane16_swap)
    u2 r = __builtin_amdgcn_permlane16_swap(__float_as_uint(v), __float_as_uint(v),
                                            false, false);
    return odd16 ? __uint_as_float(r.x) : __uint_as_float(r.y);
#else
    float t = v;
    asm volatile("s_nop 1\n\tv_permlane16_swap_b32 %0, %1" : "+v"(t), "+v"(v));
    return odd16 ? t : v;
#endif
}
// Value of v at lane^32. v_permlane32_swap_b32 swaps rows 2-3 of op0 with
// rows 0-1 of op1: res0 = rows[v0,v1,v0,v1], res1 = rows[v2,v3,v2,v3].
__device__ __forceinline__ float xor32f(float v, bool hi32) {
#if __has_builtin(__builtin_amdgcn_permlane32_swap)
    u2 r = __builtin_amdgcn_permlane32_swap(__float_as_uint(v), __float_as_uint(v),
                                            false, false);
    return hi32 ? __uint_as_float(r.x) : __uint_as_float(r.y);
#else
    float t = v;
    asm volatile("s_nop 1\n\tv_permlane32_swap_b32 %0, %1" : "+v"(t), "+v"(v));
    return hi32 ? t : v;
#endif
}

// ZERO-LDS recurrence: state tag t lives in lane t. Per step, the 64x64
// exp-domain matvec: (1) register all-gather of this lane's 16-col block via
// 15 xor-DPP movs, (2) 4 partial rows (lane^16k) over own block (same fma
// tree as R0), (3) butterfly combine across lane bits 4/5 via
// permlane16/32_swap (VALU), (4) z = readlane(x,3). No DS ops at all:
// removes the ~300-cycle LDS store->load round trip that dominated R0's
// 460 cy/step (R1-R3 all kept a DS hop on the chain and lost).
__global__ __launch_bounds__(64, 1) void crf_fwd_kernel(
    const float* __restrict__ h,
    const float* __restrict__ mask,
    const float* __restrict__ trans,
    float* __restrict__ out,
    int S)
{
    const int b = blockIdx.x;
    const int lane = threadIdx.x;
    const int i = lane & 15;            // index within 16-row
    const int beta = lane >> 4;         // 16-row index (column block)
    const bool odd16 = (beta & 1) != 0; // row parity for xor16 select
    const bool hi32 = lane >= 32;       // half for xor32 select

    // E fragment: ew[k][q] = exp(trans[lane^16k][16beta + (i^2q), 16beta + (i^(2q+1))])
    // Per-lane xor column order; pair (.x,.y) matches uu[q] below.
    f2 ew[4][8];
    #pragma unroll
    for (int k = 0; k < 4; ++k) {
        const int row = lane ^ (16 * k);
        const float* tb = trans + row * TAGS + 16 * beta;
        #pragma unroll
        for (int q = 0; q < 8; ++q) {
            f2 e;
            e.x = __expf(tb[i ^ (2 * q)]);       // exp(-10000) -> 0 exact
            e.y = __expf(tb[i ^ (2 * q + 1)]);
            ew[k][q] = e;
        }
    }

    const float* hb = h + (size_t)b * (size_t)S * TAGS + lane;
    const float* mb = mask + (size_t)b * (size_t)S;

    float x  = (lane == SOS_IDX) ? 1.0f : 0.0f;  // exp(score0), tag = lane
    float Ls = 0.0f;                              // sum of log2(z)

    // h prefetch, depth 8 (coalesced 256B/wave/step)
    float hbuf[8];
    #pragma unroll
    for (int q = 0; q < 8; ++q) {
        int t = (q < S) ? q : (S - 1);
        hbuf[q] = hb[(size_t)t * TAGS];
    }

    const int NC = S >> 6;                       // S % 64 == 0 (S = 1024)
    float mreg = mb[lane];

    for (int ch = 0; ch < NC; ++ch) {
        const int cn = (ch + 1 < NC) ? (ch + 1) : ch;
        float mreg_next = mb[(size_t)cn * 64 + lane];   // used 64 steps later

        for (int t0 = 0; t0 < 64; t0 += 8) {
            float ehq[8];
            #pragma unroll
            for (int q = 0; q < 8; ++q) ehq[q] = __expf(hbuf[q]);
            const int base = ch * 64 + t0 + 8;
            #pragma unroll
            for (int q = 0; q < 8; ++q) {
                int tn = base + q;
                if (tn > S - 1) tn = S - 1;
                hbuf[q] = hb[(size_t)tn * TAGS];
            }

            #pragma unroll
            for (int q = 0; q < 8; ++q) {
                // --- z broadcast: tag 3 state, pre-update (== R0's u_sh[3]) ---
                const float zr = rl(x, 3);
                const float m  = rl(mreg, t0 + q);          // uniform scalar
                const float z  = (zr > 0.0f) ? zr : 1.0f;   // only t=0 has 0
                const float s  = ehq[q] * __builtin_amdgcn_rcpf(z);
                const float lg = __log2f(z);

                // --- register all-gather: uu[j] = {x@(l^2j), x@(l^(2j+1))} ---
                const float u7  = DPPF(x, DPP_HMIR);        // x@(l^7)
                const float u15 = DPPF(x, DPP_MIR);         // x@(l^15)
                const float u8  = DPPF(u15, DPP_HMIR);      // x@(l^8)
                f2 uu[8];
                uu[0].x = x;                 uu[0].y = DPPF(x, DPP_X1);
                uu[1].x = DPPF(x, DPP_X2);   uu[1].y = DPPF(x, DPP_X3);
                uu[2].x = DPPF(u7, DPP_X3);  uu[2].y = DPPF(u7, DPP_X2);
                uu[3].x = DPPF(u7, DPP_X1);  uu[3].y = u7;
                uu[4].x = u8;                uu[4].y = DPPF(u8, DPP_X1);
                uu[5].x = DPPF(u8, DPP_X2);  uu[5].y = DPPF(u8, DPP_X3);
                uu[6].x = DPPF(u15, DPP_X3); uu[6].y = DPPF(u15, DPP_X2);
                uu[7].x = DPPF(u15, DPP_X1); uu[7].y = u15;

                // --- fma tree: pp[k] = partial(row lane^16k, own 16-col block) ---
                float pp[4];
                #pragma unroll
                for (int k = 0; k < 4; ++k) {
                    f2 a    = ew[k][0] * uu[0];
                    f2 bacc = ew[k][1] * uu[1];
                    a    = __builtin_elementwise_fma(ew[k][2], uu[2], a);
                    bacc = __builtin_elementwise_fma(ew[k][3], uu[3], bacc);
                    a    = __builtin_elementwise_fma(ew[k][4], uu[4], a);
                    bacc = __builtin_elementwise_fma(ew[k][5], uu[5], bacc);
                    a    = __builtin_elementwise_fma(ew[k][6], uu[6], a);
                    bacc = __builtin_elementwise_fma(ew[k][7], uu[7], bacc);
                    a = a + bacc;
                    pp[k] = a.x + a.y;
                }

                // --- butterfly combine across lane bits 4,5 (VALU-only) ---
                pp[0] += xor16f(pp[1], odd16);
                pp[2] += xor16f(pp[3], odd16);
                pp[0] += xor32f(pp[2], hi32);

                // --- tail: one mul, selects ---
                const float xnew = pp[0] * s;
                const bool mm = (m != 0.0f);                // uniform
                x  = mm ? xnew : x;
                Ls = mm ? (Ls + lg) : Ls;
            }
        }
        mreg = mreg_next;
    }

    // out[b] = ln2*Ls + log(sum_i x[i] * exp(trans[EOS, i])); tag i = lane i
    float v = x * __expf(trans[EOS_IDX * TAGS + lane]);
    #pragma unroll
    for (int off = 32; off > 0; off >>= 1) v += __shfl_xor(v, off, 64);
    if (lane == 0) out[b] = 0.69314718055994531f * Ls + __logf(v);
}

extern "C" void kernel_launch(void* const* d_in, const int* in_sizes, int n_in,
                              void* d_out, int out_size, void* d_ws, size_t ws_size,
                              hipStream_t stream) {
    const float* h     = (const float*)d_in[0];
    const float* mask  = (const float*)d_in[1];
    const float* trans = (const float*)d_in[2];
    float* out = (float*)d_out;

    const int B = out_size;                 // 512
    const int S = in_sizes[1] / B;          // 1024  (mask is B*S)

    crf_fwd_kernel<<<B, 64, 0, stream>>>(h, mask, trans, out, S);
}